// Round 5
// baseline (20875.146 us; speedup 1.0000x reference)
//
#include <hip/hip_runtime.h>
#include <math.h>

// ---------------------------------------------------------------------------
// VRNN on MI355X — round 5.
// Round 4 (CP-synchronized per-step kernels) won: 25.5 -> 18.5 ms. This round
// keeps the 3-dispatch/step skeleton but rebalances:
//   ag_k [128 WG]: A = relu(pre_enc[t] + h@enc_w1_h);  GH = h@gru_hh + b_hh
//   gemm_bt [32 WG]: E = relu(A@enc_w2 + b2)            (column-split, fast)
//   zg_k [32 WG = 4m x 8j]: ems -> z -> pz(LDS) -> gx -> GRU   (fused; pz
//        never round-trips global between dispatches; jt==0 writes outputs)
// Rationale: round-4's et_k ran on 16 WGs each streaming ~0.7MB L2-cold
// weights serially (per-WG stream-bound) and bounced pz through global.
// Pre-pass: PX=phi_x(x); PRE_ENC; GX16=PX@gru_w_ih[:512]+b_ih (fp16).
// Post-pass: prior chain (+kld), decoder chain (pz written by zg_k jt==0).
// All GEMMs: bf16 MFMA 16x16x32, fp32 accum, weights pre-transposed to [N][K].
// ---------------------------------------------------------------------------

#define TT 200
#define BB 256
#define HD 512
#define TB (TT*BB)   // 51200

typedef unsigned short u16;
typedef _Float16 f16;
typedef __attribute__((ext_vector_type(8))) short bf16x8;
typedef __attribute__((ext_vector_type(4))) float f32x4;

// output layout (fp32, concatenated flat): z, logits, em, es, pm, ps, kld
constexpr size_t OFF_Z      = 0;
constexpr size_t OFF_LOGITS = 3276800;
constexpr size_t OFF_EM     = 16384000;
constexpr size_t OFF_ES     = 19660800;
constexpr size_t OFF_PM     = 22937600;
constexpr size_t OFF_PS     = 26214400;
constexpr size_t OFF_KLD    = 29491200;

__device__ __forceinline__ u16 f2bf(float f) {
  union { float f; unsigned u; } v; v.f = f;
  return (u16)((v.u + 0x7fffu + ((v.u >> 16) & 1u)) >> 16);  // RNE
}
__device__ __forceinline__ float bf2f(u16 b) {
  union { unsigned u; float f; } v; v.u = ((unsigned)b) << 16; return v.f;
}
__device__ __forceinline__ float sp_(float x) { return (x > 15.f) ? x : log1pf(expf(x)); }
__device__ __forceinline__ float sigm_(float x) { return 1.f / (1.f + __expf(-x)); }
__device__ __forceinline__ float tanh_(float x) { return 1.f - 2.f / (1.f + __expf(2.f * x)); }

#define MFMA(a,b,c) __builtin_amdgcn_mfma_f32_16x16x32_bf16((a),(b),(c),0,0,0)

// LDS XOR-swizzle for [row][512] bf16 tiles (row stride 1024B).
#define SWZ(row, cb)  (((row) << 10) + ((cb) ^ (((row) & 7) << 4)))
// [row][64] bf16 tile, row stride 128B
#define SWZZ(row, cb) (((row) << 7)  + ((cb) ^ (((row) & 7) << 4)))

// ---------------------------------------------------------------------------
// weight cast+transpose: dst[c*R + r] = bf16(src[r*C + c])   (dst is [C][R])
// ---------------------------------------------------------------------------
#define NSEG 18
struct CastSeg { const float* src; u16* dst; int R; int C; };
struct CastArgs { CastSeg seg[NSEG]; };

__global__ __launch_bounds__(256) void cast_all(CastArgs a) {
  int idx = blockIdx.x * 256 + threadIdx.x;
  #pragma unroll 1
  for (int s = 0; s < NSEG; s++) {
    const int R = a.seg[s].R, C = a.seg[s].C;
    const int sz = R * C;
    if (idx < sz) {
      const int r = idx / C, c = idx - r * C;
      a.seg[s].dst[(size_t)c * R + r] = f2bf(a.seg[s].src[idx]);
      return;
    }
    idx -= sz;
  }
}

__global__ __launch_bounds__(256) void init_k(float* h_cur, u16* H0) {
  const int i = blockIdx.x * 256 + threadIdx.x;
  if (i < BB * HD) { h_cur[i] = 0.f; H0[i] = 0; }
}

// ---------------------------------------------------------------------------
// generic batched GEMM:  out = act( A1@Bt1^T [+ A2@Bt2^T] + bias )
// ---------------------------------------------------------------------------
struct GB {
  const void* A1; int lda1, K1, a1f32;
  const u16* Bt1;
  const u16* A2; int lda2, K2;
  const u16* Bt2;
  const float* bias;
  u16* outB; float* outF; f16* outH; int ldc;
  int tilesN; int act;   // act: 0 none, 1 relu
};

__device__ __forceinline__ bf16x8 load_a8(const void* A, int f32, size_t row, int lda, int k) {
  if (!f32) return *(const bf16x8*)((const u16*)A + row * (size_t)lda + k);
  const float* p = (const float*)A + row * (size_t)lda + k;
  f32x4 x0 = *(const f32x4*)p;
  f32x4 x1 = *(const f32x4*)(p + 4);
  bf16x8 r;
  r[0]=(short)f2bf(x0[0]); r[1]=(short)f2bf(x0[1]); r[2]=(short)f2bf(x0[2]); r[3]=(short)f2bf(x0[3]);
  r[4]=(short)f2bf(x1[0]); r[5]=(short)f2bf(x1[1]); r[6]=(short)f2bf(x1[2]); r[7]=(short)f2bf(x1[3]);
  return r;
}

__global__ __launch_bounds__(256) void gemm_bt(GB g) {
  const int tn = blockIdx.x % g.tilesN, tm = blockIdx.x / g.tilesN;
  const int m0 = tm * 64, n0 = tn * 64;
  const int v = threadIdx.x >> 6, l = threadIdx.x & 63, lm = l & 15, q = l >> 4;
  const size_t rowA = m0 + v * 16 + lm;
  f32x4 acc[4] = {};
  for (int k0 = 0; k0 < g.K1; k0 += 32) {
    bf16x8 a = load_a8(g.A1, g.a1f32, rowA, g.lda1, k0 + q * 8);
    #pragma unroll
    for (int c = 0; c < 4; c++) {
      bf16x8 b = *(const bf16x8*)(g.Bt1 + (size_t)(n0 + c * 16 + lm) * g.K1 + k0 + q * 8);
      acc[c] = MFMA(a, b, acc[c]);
    }
  }
  if (g.A2) {
    for (int k0 = 0; k0 < g.K2; k0 += 32) {
      bf16x8 a = *(const bf16x8*)(g.A2 + rowA * (size_t)g.lda2 + k0 + q * 8);
      #pragma unroll
      for (int c = 0; c < 4; c++) {
        bf16x8 b = *(const bf16x8*)(g.Bt2 + (size_t)(n0 + c * 16 + lm) * g.K2 + k0 + q * 8);
        acc[c] = MFMA(a, b, acc[c]);
      }
    }
  }
  #pragma unroll
  for (int c = 0; c < 4; c++) {
    const int col = n0 + c * 16 + lm;
    const float bs = g.bias ? g.bias[col] : 0.f;
    #pragma unroll
    for (int r = 0; r < 4; r++) {
      const size_t row = (size_t)m0 + v * 16 + q * 4 + r;
      float x = acc[c][r] + bs;
      if (g.act == 1) x = fmaxf(x, 0.f);
      if (g.outB) g.outB[row * g.ldc + col] = f2bf(x);
      if (g.outF) g.outF[row * g.ldc + col] = x;
      if (g.outH) g.outH[row * g.ldc + col] = (f16)x;
    }
  }
}

// ---------------------------------------------------------------------------
// prior mean/std heads + kld, fused (post-pass).
// ---------------------------------------------------------------------------
__global__ __launch_bounds__(256) void pms_kld(const u16* PR, const u16* pms_t,
                                               const float* pmb, const float* psb,
                                               float* out) {
  const int m0 = blockIdx.x * 64;
  const int v = threadIdx.x >> 6, l = threadIdx.x & 63, lm = l & 15, q = l >> 4;
  const size_t rowA = m0 + v * 16 + lm;
  f32x4 acc[8] = {};
  for (int k0 = 0; k0 < 512; k0 += 32) {
    bf16x8 a = *(const bf16x8*)(PR + rowA * 512 + k0 + q * 8);
    #pragma unroll
    for (int c = 0; c < 8; c++) {
      bf16x8 b = *(const bf16x8*)(pms_t + (size_t)(c * 16 + lm) * 512 + k0 + q * 8);
      acc[c] = MFMA(a, b, acc[c]);
    }
  }
  #pragma unroll
  for (int c = 0; c < 4; c++) {
    const int colz = c * 16 + lm;
    #pragma unroll
    for (int r = 0; r < 4; r++) {
      const size_t row = (size_t)m0 + v * 16 + q * 4 + r;
      const float pm = acc[c][r] + pmb[colz];
      const float ps = sp_(acc[c + 4][r] + psb[colz]);
      const size_t oi = row * 64 + colz;
      const float em = out[OFF_EM + oi], es = out[OFF_ES + oi];
      const float d = em - pm;
      const float kld = 0.5f * (2.f * logf(ps) - 2.f * logf(es)
                                + (es * es + d * d) / (ps * ps) - 1.f);
      out[OFF_PM + oi] = pm;
      out[OFF_PS + oi] = ps;
      out[OFF_KLD + oi] = kld;
    }
  }
}

// ---------------------------------------------------------------------------
// per-step kernels (CP-synchronized)
// ---------------------------------------------------------------------------
struct SP {
  const u16 *pre_enc;   // BUF0 [TT][256][512] bf16 (slice t read by ag_k)
  u16 *pzbuf;           // == BUF0 (slice t overwritten with pz by zg_k jt==0)
  u16 *H;               // [(TT+1)][256][512] bf16; H[t] = h entering step t
  float *h_cur;         // [256][512] fp32 carry
  u16 *Abuf;            // [256][512] bf16 step scratch
  u16 *Ebuf;            // [256][512] bf16 step scratch
  float *GH;            // [256][1536] fp32 step scratch (h@gru_hh + b_hh)
  const f16 *gx;        // [TB][1536] fp16: px@gru_w_ih[:512] + b_ih
  const u16 *enc_w1_h_t, *ems_t, *phi_z_t, *gru_hh_t, *gru_ih_pz_t;
  const float *enc_mean_b, *enc_std_b, *phi_z_b, *gru_b_hh;
  const float *eps;
  float *out;
};

// K1: 128 WGs = 4 m-tiles x 32 n-tiles (n<8 -> A cols, n>=8 -> GH gate cols)
__global__ __launch_bounds__(256) void ag_k(SP s, int t) {
  const int tn = blockIdx.x & 31, tm = blockIdx.x >> 5;
  const int v = threadIdx.x >> 6, l = threadIdx.x & 63, lm = l & 15, q = l >> 4;
  const int m0 = tm * 64;
  const size_t rowA = m0 + v * 16 + lm;
  const u16* Ht = s.H + (size_t)t * (BB * HD);
  const bool isA = (tn < 8);
  const int n0 = isA ? tn * 64 : (tn - 8) * 64;
  const u16* Bt = isA ? s.enc_w1_h_t : s.gru_hh_t;
  f32x4 acc[4] = {};
  for (int k0 = 0; k0 < 512; k0 += 32) {
    bf16x8 a = *(const bf16x8*)(Ht + rowA * 512 + k0 + q * 8);
    #pragma unroll
    for (int c = 0; c < 4; c++) {
      bf16x8 b = *(const bf16x8*)(Bt + (size_t)(n0 + c * 16 + lm) * 512 + k0 + q * 8);
      acc[c] = MFMA(a, b, acc[c]);
    }
  }
  if (isA) {
    const u16* pre = s.pre_enc + (size_t)t * (BB * HD);
    #pragma unroll
    for (int c = 0; c < 4; c++) {
      const int col = n0 + c * 16 + lm;
      #pragma unroll
      for (int r = 0; r < 4; r++) {
        const int row = m0 + v * 16 + q * 4 + r;
        const float x = acc[c][r] + bf2f(pre[(size_t)row * 512 + col]);
        s.Abuf[(size_t)row * 512 + col] = f2bf(fmaxf(x, 0.f));
      }
    }
  } else {
    #pragma unroll
    for (int c = 0; c < 4; c++) {
      const int colg = n0 + c * 16 + lm;
      const float bs = s.gru_b_hh[colg];
      #pragma unroll
      for (int r = 0; r < 4; r++) {
        const int row = m0 + v * 16 + q * 4 + r;
        s.GH[(size_t)row * 1536 + colg] = acc[c][r] + bs;
      }
    }
  }
}

// K3: 32 WGs = 4 m-tiles x 8 j-tiles.
// Per WG (rows m0..m0+64): ems (all 128 cols) -> z -> pz (LDS, all 512 cols)
// -> gx for j-cols j0..j0+64 (3 gates) -> GRU update.
// jt==0 WGs additionally write z/em/es outputs and pz to global (decoder).
__global__ __launch_bounds__(256) void zg_k(SP s, int t) {
  const int jt = blockIdx.x & 7, tm = blockIdx.x >> 3;
  const int tid = threadIdx.x;
  const int v = tid >> 6, l = tid & 63, lm = l & 15, q = l >> 4;
  const int m0 = tm * 64, j0 = jt * 64;

  __shared__ float emsb[64 * 128];   // 32KB
  __shared__ u16 zb[64 * 64];        // 8KB  (swizzled, SWZZ)
  __shared__ u16 pzl[64 * 512];      // 64KB (swizzled, SWZ)

  // ---- a) ems = E @ ems_t (+bias); wave v -> cols 32v..32v+32 ----
  {
    const int cb = v * 32;
    f32x4 acc[4][2] = {};
    for (int k0 = 0; k0 < 512; k0 += 32) {
      bf16x8 b0 = *(const bf16x8*)(s.ems_t + (size_t)(cb + lm) * 512 + k0 + q * 8);
      bf16x8 b1 = *(const bf16x8*)(s.ems_t + (size_t)(cb + 16 + lm) * 512 + k0 + q * 8);
      #pragma unroll
      for (int mt = 0; mt < 4; mt++) {
        bf16x8 a = *(const bf16x8*)(s.Ebuf + (size_t)(m0 + mt * 16 + lm) * 512 + k0 + q * 8);
        acc[mt][0] = MFMA(a, b0, acc[mt][0]);
        acc[mt][1] = MFMA(a, b1, acc[mt][1]);
      }
    }
    #pragma unroll
    for (int ct = 0; ct < 2; ct++) {
      const int col = cb + ct * 16 + lm;
      const float bs = (col < 64) ? s.enc_mean_b[col] : s.enc_std_b[col - 64];
      #pragma unroll
      for (int mt = 0; mt < 4; mt++)
        #pragma unroll
        for (int r = 0; r < 4; r++)
          emsb[(mt * 16 + q * 4 + r) * 128 + col] = acc[mt][ct][r] + bs;
    }
  }
  __syncthreads();

  // ---- b) z = eps*sp(es)+em; jt==0 writes z/em/es outputs; all write zb ----
  #pragma unroll
  for (int i = 0; i < 16; i++) {
    const int e = tid + i * 256;               // 64 rows x 64 cols
    const int rr = e >> 6, cc = e & 63;
    const float em = emsb[rr * 128 + cc];
    const float es = sp_(emsb[rr * 128 + 64 + cc]);
    const int row = m0 + rr;
    const size_t oi = ((size_t)t * BB + row) * 64 + cc;
    const float z = s.eps[oi] * es + em;
    if (jt == 0) {
      s.out[OFF_Z + oi]  = z;
      s.out[OFF_EM + oi] = em;
      s.out[OFF_ES + oi] = es;
    }
    *(u16*)((char*)zb + SWZZ(rr, cc * 2)) = f2bf(z);
  }
  __syncthreads();

  // ---- c) pz = relu(z @ phi_z + b); wave v -> its rows 16v..16v+16, all 512 ----
  {
    f32x4 pa[32];
    #pragma unroll
    for (int n = 0; n < 32; n++) pa[n] = (f32x4){0.f, 0.f, 0.f, 0.f};
    #pragma unroll
    for (int k0 = 0; k0 < 64; k0 += 32) {
      bf16x8 a = *(const bf16x8*)((const char*)zb + SWZZ(v * 16 + lm, (k0 + q * 8) * 2));
      #pragma unroll
      for (int n = 0; n < 32; n++) {
        bf16x8 b = *(const bf16x8*)(s.phi_z_t + (size_t)(n * 16 + lm) * 64 + k0 + q * 8);
        pa[n] = MFMA(a, b, pa[n]);
      }
    }
    u16* pzg = s.pzbuf + (size_t)t * (BB * HD);
    #pragma unroll
    for (int n = 0; n < 32; n++) {
      const int col = n * 16 + lm;
      const float bs = s.phi_z_b[col];
      #pragma unroll
      for (int r = 0; r < 4; r++) {
        const int rloc = v * 16 + q * 4 + r;
        const u16 val = f2bf(fmaxf(pa[n][r] + bs, 0.f));
        *(u16*)((char*)pzl + SWZ(rloc, col * 2)) = val;
        if (jt == 0) pzg[(size_t)(m0 + rloc) * 512 + col] = val;
      }
    }
  }
  __syncthreads();

  // ---- d) gx = gx16 + pz@gru_ih_pz (3 gates, j-cols j0..j0+64); e) GRU ----
  {
    f32x4 acc[3][4] = {};
    for (int k0 = 0; k0 < 512; k0 += 32) {
      bf16x8 a = *(const bf16x8*)((const char*)pzl + SWZ(v * 16 + lm, (k0 + q * 8) * 2));
      #pragma unroll
      for (int g = 0; g < 3; g++) {
        #pragma unroll
        for (int c = 0; c < 4; c++) {
          bf16x8 b = *(const bf16x8*)(s.gru_ih_pz_t
                       + (size_t)(g * 512 + j0 + c * 16 + lm) * 512 + k0 + q * 8);
          acc[g][c] = MFMA(a, b, acc[g][c]);
        }
      }
    }
    const f16* gxt = s.gx + (size_t)t * BB * 1536;
    u16* Hn = s.H + (size_t)(t + 1) * (BB * HD);
    #pragma unroll
    for (int c = 0; c < 4; c++) {
      const int j = j0 + c * 16 + lm;
      #pragma unroll
      for (int r = 0; r < 4; r++) {
        const int row = m0 + v * 16 + q * 4 + r;
        const size_t base = (size_t)row * 1536;
        const float xr = acc[0][c][r] + (float)gxt[base + j];
        const float xz = acc[1][c][r] + (float)gxt[base + 512 + j];
        const float xn = acc[2][c][r] + (float)gxt[base + 1024 + j];
        const float hr = s.GH[base + j];
        const float hz = s.GH[base + 512 + j];
        const float hn = s.GH[base + 1024 + j];
        const float rg = sigm_(xr + hr);
        const float uu = sigm_(xz + hz);
        const float nn = tanh_(xn + rg * hn);
        const float hold = s.h_cur[(size_t)row * 512 + j];
        const float hnew = (1.f - uu) * nn + uu * hold;
        s.h_cur[(size_t)row * 512 + j] = hnew;
        Hn[(size_t)row * 512 + j] = f2bf(hnew);
      }
    }
  }
}

// ---------------------------------------------------------------------------
extern "C" void kernel_launch(void* const* d_in, const int* in_sizes, int n_in,
                              void* d_out, int out_size, void* d_ws, size_t ws_size,
                              hipStream_t stream) {
  (void)in_sizes; (void)n_in; (void)out_size; (void)ws_size;
  char* ws = (char*)d_ws;
  float* out = (float*)d_out;
  auto in = [&](int i) { return (const float*)d_in[i]; };

  size_t o = 0;
  auto take = [&](size_t bytes) { size_t r = o; o += (bytes + 255) & ~(size_t)255; return r; };
  const size_t oPhiXW1  = take(512 * 128 * 2);
  const size_t oPhiXW2  = take(512 * 512 * 2);
  const size_t oEncW1px = take(512 * 512 * 2);
  const size_t oEncW1h  = take(512 * 512 * 2);
  const size_t oEncW2   = take(512 * 512 * 2);
  const size_t oEms     = take(128 * 512 * 2);
  const size_t oPhiZ    = take(512 * 64 * 2);
  const size_t oPriorW  = take(512 * 512 * 2);
  const size_t oPriorMs = take(128 * 512 * 2);
  const size_t oDecW1pz = take(512 * 512 * 2);
  const size_t oDecW1h  = take(512 * 512 * 2);
  const size_t oDecW2   = take(512 * 512 * 2);
  const size_t oDecLog  = take(256 * 512 * 2);
  const size_t oGruIhPx = take((size_t)1536 * 512 * 2);
  const size_t oGruIhPz = take((size_t)1536 * 512 * 2);
  const size_t oGruHh   = take((size_t)1536 * 512 * 2);
  const size_t oBuf0    = take((size_t)TB * 512 * 2);
  const size_t oBuf1    = take((size_t)TB * 512 * 2);
  const size_t oH       = take((size_t)(TT + 1) * BB * 512 * 2);
  const size_t oHcur    = take((size_t)BB * 512 * 4);
  const size_t oAbuf    = take((size_t)BB * 512 * 2);
  const size_t oEbuf    = take((size_t)BB * 512 * 2);
  const size_t oGH      = take((size_t)BB * 1536 * 4);
  const size_t oGX      = take((size_t)TB * 1536 * 2);   // fp16 gxpx

  auto W = [&](size_t off) { return (u16*)(ws + off); };
  u16* BUF0 = W(oBuf0);
  u16* BUF1 = W(oBuf1);
  u16* Hbuf = W(oH);
  float* h_cur = (float*)(ws + oHcur);
  f16* GX16 = (f16*)(ws + oGX);

  // --- weight cast+transpose (one kernel, 18 segments) ---
  CastArgs ca;
  int si = 0;
  auto seg = [&](const float* src, u16* dst, int R, int C) { ca.seg[si++] = {src, dst, R, C}; };
  seg(in(2), W(oPhiXW1), 128, 512);
  seg(in(4), W(oPhiXW2), 512, 512);
  seg(in(8), W(oEncW1px), 512, 512);
  seg(in(8) + 512 * 512, W(oEncW1h), 512, 512);
  seg(in(10), W(oEncW2), 512, 512);
  seg(in(12), W(oEms), 512, 64);
  seg(in(14), W(oEms) + 64 * 512, 512, 64);
  seg(in(6), W(oPhiZ), 64, 512);
  seg(in(16), W(oPriorW), 512, 512);
  seg(in(18), W(oPriorMs), 512, 64);
  seg(in(20), W(oPriorMs) + 64 * 512, 512, 64);
  seg(in(22), W(oDecW1pz), 512, 512);
  seg(in(22) + 512 * 512, W(oDecW1h), 512, 512);
  seg(in(24), W(oDecW2), 512, 512);
  seg(in(26), W(oDecLog), 512, 256);
  seg(in(28), W(oGruIhPx), 512, 1536);
  seg(in(28) + 512 * 1536, W(oGruIhPz), 512, 1536);
  seg(in(30), W(oGruHh), 512, 1536);
  hipLaunchKernelGGL(cast_all, dim3(18816), dim3(256), 0, stream, ca);
  hipLaunchKernelGGL(init_k, dim3(512), dim3(256), 0, stream, h_cur, Hbuf);

  auto gemm = [&](const void* A1, int lda1, int K1, int a1f32, const u16* Bt1,
                  const u16* A2, int lda2, int K2, const u16* Bt2,
                  const float* bias, u16* outB, float* outF, f16* outH,
                  int ldc, int M, int N, int act) {
    GB g;
    g.A1 = A1; g.lda1 = lda1; g.K1 = K1; g.a1f32 = a1f32; g.Bt1 = Bt1;
    g.A2 = A2; g.lda2 = lda2; g.K2 = K2; g.Bt2 = Bt2;
    g.bias = bias; g.outB = outB; g.outF = outF; g.outH = outH; g.ldc = ldc;
    g.tilesN = N / 64; g.act = act;
    hipLaunchKernelGGL(gemm_bt, dim3((M / 64) * (N / 64)), dim3(256), 0, stream, g);
  };

  // --- pre-pass ---
  // PX1 = relu(x @ phi_x_w1 + b1)          -> BUF0
  gemm(in(0), 128, 128, 1, W(oPhiXW1), nullptr, 0, 0, nullptr, in(3), BUF0, nullptr, nullptr, 512, TB, 512, 1);
  // PX  = relu(PX1 @ phi_x_w2 + b2)        -> BUF1
  gemm(BUF0, 512, 512, 0, W(oPhiXW2), nullptr, 0, 0, nullptr, in(5), BUF1, nullptr, nullptr, 512, TB, 512, 1);
  // PRE_ENC = PX @ enc_w1[:512] + enc_b1   -> BUF0
  gemm(BUF1, 512, 512, 0, W(oEncW1px), nullptr, 0, 0, nullptr, in(9), BUF0, nullptr, nullptr, 512, TB, 512, 0);
  // GX16 = PX @ gru_w_ih[:512] + b_ih      -> fp16
  gemm(BUF1, 512, 512, 0, W(oGruIhPx), nullptr, 0, 0, nullptr, in(29), nullptr, nullptr, GX16, 1536, TB, 1536, 0);

  // --- sequential scan: 3 CP-synchronized kernels per step ---
  SP sp;
  sp.pre_enc = BUF0; sp.pzbuf = BUF0;
  sp.H = Hbuf; sp.h_cur = h_cur;
  sp.Abuf = W(oAbuf); sp.Ebuf = W(oEbuf);
  sp.GH = (float*)(ws + oGH); sp.gx = GX16;
  sp.enc_w1_h_t = W(oEncW1h); sp.ems_t = W(oEms);
  sp.phi_z_t = W(oPhiZ); sp.gru_hh_t = W(oGruHh); sp.gru_ih_pz_t = W(oGruIhPz);
  sp.enc_mean_b = in(13); sp.enc_std_b = in(15);
  sp.phi_z_b = in(7); sp.gru_b_hh = in(31);
  sp.eps = in(1); sp.out = out;

  // E-step GEMM arg (t-independent: Abuf -> Ebuf)
  GB ge;
  ge.A1 = W(oAbuf); ge.lda1 = 512; ge.K1 = 512; ge.a1f32 = 0; ge.Bt1 = W(oEncW2);
  ge.A2 = nullptr; ge.lda2 = 0; ge.K2 = 0; ge.Bt2 = nullptr;
  ge.bias = in(11); ge.outB = W(oEbuf); ge.outF = nullptr; ge.outH = nullptr;
  ge.ldc = 512; ge.tilesN = 8; ge.act = 1;

  for (int t = 0; t < TT; t++) {
    hipLaunchKernelGGL(ag_k,    dim3(128), dim3(256), 0, stream, sp, t);
    hipLaunchKernelGGL(gemm_bt, dim3(32),  dim3(256), 0, stream, ge);
    hipLaunchKernelGGL(zg_k,    dim3(32),  dim3(256), 0, stream, sp, t);
  }

  // --- post-pass (batched over all T; BUF0 now holds PZ written by zg_k) ---
  // PR = relu(Hprev @ prior_w + b)         -> BUF1
  gemm(Hbuf, 512, 512, 0, W(oPriorW), nullptr, 0, 0, nullptr, in(17), BUF1, nullptr, nullptr, 512, TB, 512, 1);
  // pm/ps/kld                              -> d_out
  hipLaunchKernelGGL(pms_kld, dim3(TB / 64), dim3(256), 0, stream,
                     BUF1, W(oPriorMs), in(19), in(21), out);
  // DH1 = relu(PZ@dec_w1[:512] + Hprev@dec_w1[512:] + b1) -> BUF1
  gemm(BUF0, 512, 512, 0, W(oDecW1pz), Hbuf, 512, 512, W(oDecW1h), in(23), BUF1, nullptr, nullptr, 512, TB, 512, 1);
  // D = relu(DH1 @ dec_w2 + b2)            -> BUF0
  gemm(BUF1, 512, 512, 0, W(oDecW2), nullptr, 0, 0, nullptr, in(25), BUF0, nullptr, nullptr, 512, TB, 512, 1);
  // logits = D @ dec_logits + b            -> d_out fp32
  gemm(BUF0, 512, 512, 0, W(oDecLog), nullptr, 0, 0, nullptr, in(27), nullptr, out + OFF_LOGITS, nullptr, 256, TB, 256, 0);
}